// Round 12
// baseline (101.327 us; speedup 1.0000x reference)
//
#include <hip/hip_runtime.h>
#include <hip/hip_bf16.h>
#include <math.h>

#define B_ 1024
#define S_ 512
#define E_ 1024
#define D_ 2048
#define SMOOTH 10.0f

typedef __attribute__((ext_vector_type(8))) short bf16x8;
typedef __attribute__((ext_vector_type(4))) short s16x4;
typedef __attribute__((ext_vector_type(4))) float f32x4;

__device__ __forceinline__ short f2bf(float f) {
    __hip_bfloat16 h = __float2bfloat16(f);
    short s; __builtin_memcpy(&s, &h, 2); return s;
}

__device__ __forceinline__ void gload16(const short* g, short* l) {
    __builtin_amdgcn_global_load_lds(
        (const __attribute__((address_space(1))) void*)(g),
        (__attribute__((address_space(3))) void*)(l), 16, 0, 0);
}

__inline__ __device__ float waveReduceMax(float v) {
#pragma unroll
    for (int o = 32; o; o >>= 1) v = fmaxf(v, __shfl_xor(v, o));
    return v;
}
__inline__ __device__ float waveReduceSum(float v) {
#pragma unroll
    for (int o = 32; o; o >>= 1) v += __shfl_xor(v, o);
    return v;
}

// ---------------- args ----------------
struct KArgs {
    const float *cf, *emb, *fc1w, *fc2w, *bn1g, *bn1b, *bn2g, *bn2b, *fc3w;
    short *A1, *A2, *Bt1, *Bt2, *cfT, *Ws, *Wv3, *A4;
    float *invn, *Z1, *Z2, *part1, *part2, *P1, *P2, *P3, *emb_pre;
    float *weights_v, *emb_concept;
};

// ---------------- vectorized transpose (32x32 tile via LDS), bf16 out ----------------
__device__ __forceinline__ void transpose_bf(const float* __restrict__ in,
                                             short* __restrict__ out,
                                             int C, int r0, int c0, int ldo,
                                             int tid, float (*t)[33]) {
    {   // load: 32 rows x 8 float4
        int r = tid >> 3, cq = tid & 7;
        f32x4 v = *(const f32x4*)(in + (size_t)(r0 + r) * C + c0 + cq * 4);
#pragma unroll
        for (int i = 0; i < 4; i++) t[r][cq * 4 + i] = v[i];
    }
    __syncthreads();
    {   // store: 32 cols x 8 short4 (4 consecutive rows each)
        int rq = tid & 7, cy = tid >> 3;
        s16x4 o;
#pragma unroll
        for (int i = 0; i < 4; i++) o[i] = f2bf(t[rq * 4 + i][cy]);
        *(s16x4*)(out + (size_t)(c0 + cy) * ldo + r0 + rq * 4) = o;
    }
}

// ---------------- prep: conversions / transposes / invnorm, task-segmented ----------------
// [0,512):      cf row -> A1 bf16 + invn
// [512,1024):   emb (2 rows) -> A2 bf16
// [1024,3072):  fc1_w -> Bt1 bf16-T
// [3072,4096):  fc2_w -> Bt2 bf16-T
// [4096,5120):  cf -> cfT bf16-T
__global__ __launch_bounds__(256) void prep_k(KArgs a) {
    __shared__ float t[32][33];
    __shared__ float red[4];
    const int task = blockIdx.x;
    const int tid = threadIdx.x;
    if (task < 512) {
        int row = task;
        const float* x = a.cf + (size_t)row * D_;
        short* aa = a.A1 + (size_t)row * D_;
        float ss = 0.f;
#pragma unroll
        for (int j = 0; j < 2; j++) {
            int i = (j * 256 + tid) * 4;
            f32x4 v = *(const f32x4*)(x + i);
            s16x4 o;
#pragma unroll
            for (int q = 0; q < 4; q++) { o[q] = f2bf(v[q]); ss += v[q] * v[q]; }
            *(s16x4*)(aa + i) = o;
        }
        ss = waveReduceSum(ss);
        if ((tid & 63) == 0) red[tid >> 6] = ss;
        __syncthreads();
        if (tid == 0) {
            float s = red[0] + red[1] + red[2] + red[3];
            a.invn[row] = 1.0f / (sqrtf(s) + 1e-8f);
        }
    } else if (task < 1024) {
        int r0 = (task - 512) * 2;
#pragma unroll
        for (int rr = 0; rr < 2; rr++) {
            int row = r0 + rr;
            int i = tid * 4;
            f32x4 v = *(const f32x4*)(a.emb + (size_t)row * E_ + i);
            s16x4 o;
#pragma unroll
            for (int q = 0; q < 4; q++) o[q] = f2bf(v[q]);
            *(s16x4*)(a.A2 + (size_t)row * E_ + i) = o;
        }
    } else if (task < 3072) {
        int b2 = task - 1024;
        int c0 = (b2 & 31) * 32;
        int r0 = (b2 >> 5) * 32;
        transpose_bf(a.fc1w, a.Bt1, E_, r0, c0, D_, tid, t);
    } else if (task < 4096) {
        int b2 = task - 3072;
        int c0 = (b2 & 31) * 32;
        int r0 = (b2 >> 5) * 32;
        transpose_bf(a.fc2w, a.Bt2, E_, r0, c0, E_, tid, t);
    } else {
        int b2 = task - 4096;
        int c0 = (b2 & 63) * 32;
        int r0 = (b2 >> 6) * 32;
        transpose_bf(a.cf, a.cfT, D_, r0, c0, S_, tid, t);
    }
}

// ---------------- 128x128 MFMA GEMM core, nt form, split-K (proven R8 config) ----------------
struct GP {
    const short* A;
    const short* Bm;
    float* P;
    int M, N, K, Kc, nx, ny;
};

__device__ __forceinline__ void gemm128_core(const GP g, int bid, short* lds) {
    const int tid = threadIdx.x;
    const int per = g.nx * g.ny;
    const int z = bid / per, rem = bid % per;
    const int by = rem / g.nx, bx = rem % g.nx;
    const int bm = by * 128, bn = bx * 128;
    const int kz = z * g.Kc;
    float* C = g.P + (size_t)z * g.M * g.N;
    const short* gA = g.A + (size_t)bm * g.K + kz;
    const short* gB = g.Bm + (size_t)bn * g.K + kz;

    size_t soff[4];
#pragma unroll
    for (int i = 0; i < 4; i++) {
        int ci = tid + i * 256;
        int row = ci >> 3, c = ci & 7;
        soff[i] = (size_t)row * g.K + ((c ^ (row & 7)) << 3);
    }

    auto stage = [&](int buf, int kt) {
        short* base = lds + buf * 16384;
#pragma unroll
        for (int i = 0; i < 4; i++) {
            gload16(gA + soff[i] + kt, base + tid * 8 + i * 2048);
            gload16(gB + soff[i] + kt, base + 8192 + tid * 8 + i * 2048);
        }
    };

    const int lane = tid & 63, wid = tid >> 6;
    const int wr = wid >> 1, wc = wid & 1;
    const int r16 = lane & 15, kg = lane >> 4;
    const int rs7 = (r16 & 7);

    f32x4 acc[4][4] = {};
    const int nt = g.Kc >> 6;

    stage(0, 0);
    for (int t = 0; t < nt; ++t) {
        __syncthreads();
        if (t + 1 < nt) stage((t + 1) & 1, (t + 1) << 6);
        const short* LA = lds + (t & 1) * 16384;
        const short* LB = LA + 8192;
#pragma unroll
        for (int ks = 0; ks < 2; ++ks) {
            const int sw = ((ks * 4 + kg) ^ rs7) << 3;
            bf16x8 a[4], b[4];
#pragma unroll
            for (int m = 0; m < 4; m++)
                a[m] = *(const bf16x8*)(LA + (wr * 64 + m * 16 + r16) * 64 + sw);
#pragma unroll
            for (int n = 0; n < 4; n++)
                b[n] = *(const bf16x8*)(LB + (wc * 64 + n * 16 + r16) * 64 + sw);
#pragma unroll
            for (int m = 0; m < 4; m++)
#pragma unroll
                for (int n = 0; n < 4; n++)
                    acc[m][n] = __builtin_amdgcn_mfma_f32_16x16x32_bf16(a[m], b[n], acc[m][n], 0, 0, 0);
        }
    }

#pragma unroll
    for (int m = 0; m < 4; m++)
#pragma unroll
        for (int n = 0; n < 4; n++) {
            int col = bn + wc * 64 + n * 16 + r16;
#pragma unroll
            for (int r = 0; r < 4; r++) {
                int row = bm + wr * 64 + m * 16 + kg * 4 + r;
                C[(size_t)row * g.N + col] = acc[m][n][r];
            }
        }
}

__global__ __launch_bounds__(256) void gemm_dual(GP g0, GP g1, int n0) {
    __shared__ short lds[32768];
    int bid = blockIdx.x;
    if (bid < n0) gemm128_core(g0, bid, lds);
    else gemm128_core(g1, bid - n0, lds);
}

__global__ __launch_bounds__(256) void gemm_one(GP g) {
    __shared__ short lds[32768];
    gemm128_core(g, blockIdx.x, lds);
}

// ---------------- split-K reduce + BN partial stats, float4 ----------------
// 1D grid 192: bid<64 -> branch1 (8 rows, KS=4); bid>=64 -> branch2 (8 rows, KS=2)
__global__ __launch_bounds__(256) void bn_stats12(KArgs a) {
    const int tid = threadIdx.x;
    const int c4 = tid * 4;
    const bool br1 = blockIdx.x < 64;
    const int y = br1 ? blockIdx.x : (blockIdx.x - 64);
    const int KS = br1 ? 4 : 2;
    const float* P = br1 ? a.P1 : a.P2;
    float* Z = br1 ? a.Z1 : a.Z2;
    float* part = br1 ? a.part1 : a.part2;
    const size_t slice = (size_t)(br1 ? S_ : B_) * E_;
    const int r0 = y * 8;

    f32x4 s = {0, 0, 0, 0}, sq = {0, 0, 0, 0};
    for (int r = r0; r < r0 + 8; r++) {
        f32x4 z = {0, 0, 0, 0};
        for (int k = 0; k < KS; k++)
            z += *(const f32x4*)(P + (size_t)k * slice + (size_t)r * E_ + c4);
        *(f32x4*)(Z + (size_t)r * E_ + c4) = z;
        s += z;
        sq += z * z;
    }
    *(f32x4*)(part + (size_t)y * 2 * E_ + c4) = s;
    *(f32x4*)(part + (size_t)y * 2 * E_ + E_ + c4) = sq;
}

// ---------------- BN finalize + tanh (+fc3 scale) -> bf16, float4 ----------------
// 1D grid 96: bid<32 -> branch1 (16 rows, NS=64); bid>=32 -> branch2 (16 rows, NS=128)
__global__ __launch_bounds__(256) void bn_apply12(KArgs a) {
    const int tid = threadIdx.x;
    const int c4 = tid * 4;
    const bool br1 = blockIdx.x < 32;
    const int y = br1 ? blockIdx.x : (blockIdx.x - 32);
    const int NS = br1 ? 64 : 128;
    const float* part = br1 ? a.part1 : a.part2;
    f32x4 s = {0, 0, 0, 0}, sq = {0, 0, 0, 0};
    for (int k = 0; k < NS; k++) {
        s += *(const f32x4*)(part + (size_t)k * 2 * E_ + c4);
        sq += *(const f32x4*)(part + (size_t)k * 2 * E_ + E_ + c4);
    }
    const float invR = br1 ? (1.0f / 512.0f) : (1.0f / 1024.0f);
    f32x4 g = *(const f32x4*)((br1 ? a.bn1g : a.bn2g) + c4);
    f32x4 b = *(const f32x4*)((br1 ? a.bn1b : a.bn2b) + c4);
    f32x4 Aa, Bb, sc;
#pragma unroll
    for (int q = 0; q < 4; q++) {
        float mu = s[q] * invR;
        float var = sq[q] * invR - mu * mu;
        float rstd = rsqrtf(var + 1e-5f);
        Aa[q] = g[q] * rstd;
        Bb[q] = b[q] - Aa[q] * mu;
    }
    if (br1) { sc[0] = sc[1] = sc[2] = sc[3] = 1.0f; }
    else sc = *(const f32x4*)(a.fc3w + c4);
    const float* Z = br1 ? a.Z1 : a.Z2;
    short* W = br1 ? a.Ws : a.Wv3;
    const int r0 = y * 16;
    for (int r = r0; r < r0 + 16; r++) {
        f32x4 z = *(const f32x4*)(Z + (size_t)r * E_ + c4);
        s16x4 o;
#pragma unroll
        for (int q = 0; q < 4; q++)
            o[q] = f2bf(tanhf(fmaf(z[q], Aa[q], Bb[q])) * sc[q]);
        *(s16x4*)(W + (size_t)r * E_ + c4) = o;
    }
}

// ---------------- split-K reduce (KS=4) + row softmax, float4, 2 rows/block ----------------
__global__ __launch_bounds__(256) void softmax_k(KArgs a) {
    __shared__ float redm[4], reds[4];
    const int tid = threadIdx.x;
    const int row = blockIdx.x * 2 + (tid >> 7);
    const int li = (tid & 127) * 4;
    const int wid = tid >> 6;
    const size_t base = (size_t)row * S_ + li;
    f32x4 v = {0, 0, 0, 0};
#pragma unroll
    for (int k = 0; k < 4; k++)
        v += *(const f32x4*)(a.P3 + (size_t)k * B_ * S_ + base);
    v *= SMOOTH;
    float m = fmaxf(fmaxf(v[0], v[1]), fmaxf(v[2], v[3]));
    m = waveReduceMax(m);
    if ((tid & 63) == 0) redm[wid] = m;
    __syncthreads();
    m = (tid < 128) ? fmaxf(redm[0], redm[1]) : fmaxf(redm[2], redm[3]);
    f32x4 e;
#pragma unroll
    for (int q = 0; q < 4; q++) e[q] = __expf(v[q] - m);
    float es = waveReduceSum(e[0] + e[1] + e[2] + e[3]);
    if ((tid & 63) == 0) reds[wid] = es;
    __syncthreads();
    float ssum = (tid < 128) ? (reds[0] + reds[1]) : (reds[2] + reds[3]);
    float inv = 1.0f / ssum;
    f32x4 wv = e * inv;
    *(f32x4*)(a.weights_v + base) = wv;
    f32x4 nv = *(const f32x4*)(a.invn + li);
    s16x4 o;
#pragma unroll
    for (int q = 0; q < 4; q++) o[q] = f2bf(wv[q] * nv[q]);
    *(s16x4*)(a.A4 + base) = o;
}

// ---------------- row l2norm -> output, float4 ----------------
__global__ __launch_bounds__(256) void rownorm_k(KArgs a) {
    __shared__ float red[4];
    const int row = blockIdx.x;
    const int tid = threadIdx.x;
    const size_t base = (size_t)row * D_ + tid * 4;
    f32x4 v0 = *(const f32x4*)(a.emb_pre + base);
    f32x4 v1 = *(const f32x4*)(a.emb_pre + base + 1024);
    float ss = v0[0]*v0[0] + v0[1]*v0[1] + v0[2]*v0[2] + v0[3]*v0[3]
             + v1[0]*v1[0] + v1[1]*v1[1] + v1[2]*v1[2] + v1[3]*v1[3];
    ss = waveReduceSum(ss);
    if ((tid & 63) == 0) red[tid >> 6] = ss;
    __syncthreads();
    ss = red[0] + red[1] + red[2] + red[3];
    float sc = 1.0f / (sqrtf(ss) + 1e-8f);
    *(f32x4*)(a.emb_concept + base) = v0 * sc;
    *(f32x4*)(a.emb_concept + base + 1024) = v1 * sc;
}

extern "C" void kernel_launch(void* const* d_in, const int* in_sizes, int n_in,
                              void* d_out, int out_size, void* d_ws, size_t ws_size,
                              hipStream_t stream) {
    float* out = (float*)d_out;
    const size_t MB = 1024 * 1024;
    char* w = (char*)d_ws;

    KArgs a;
    a.cf   = (const float*)d_in[1];
    a.emb  = (const float*)d_in[0];
    a.fc1w = (const float*)d_in[3];
    a.fc2w = (const float*)d_in[7];
    a.bn1g = (const float*)d_in[5];
    a.bn1b = (const float*)d_in[6];
    a.bn2g = (const float*)d_in[9];
    a.bn2b = (const float*)d_in[10];
    a.fc3w = (const float*)d_in[11];
    a.Bt1  = (short*)(w + 0 * MB);            // 4MB
    a.Bt2  = (short*)(w + 4 * MB);            // 2MB
    a.A1   = (short*)(w + 6 * MB);            // 2MB
    a.A2   = (short*)(w + 8 * MB);            // 2MB
    a.cfT  = (short*)(w + 10 * MB);           // 2MB
    a.Ws   = (short*)(w + 12 * MB);           // 1MB
    a.Wv3  = (short*)(w + 13 * MB);           // 2MB
    a.A4   = (short*)(w + 15 * MB);           // 1MB
    a.invn = (float*)(w + 16 * MB);           // 2KB
    a.Z1   = (float*)(w + 17 * MB);           // 2MB
    a.Z2   = (float*)(w + 19 * MB);           // 4MB
    a.part1 = (float*)(w + 23 * MB);          // 64*2*E*4 = 512KB
    a.part2 = (float*)(w + 23 * MB + 512 * 1024);  // 128*2*E*4 = 1MB
    a.P1   = (float*)(w + 25 * MB);           // KS=4 x 2MB = 8MB
    a.P2   = (float*)(w + 33 * MB);           // KS=2 x 4MB = 8MB
    a.P3   = (float*)(w + 25 * MB);           // 8MB (aliases P1, dead after bn_stats)
    a.emb_pre = (float*)(w + 33 * MB);        // 8MB (aliases P2, dead after bn_stats)
    a.emb_concept = out;
    a.weights_v   = out + (size_t)B_ * D_;

    // 1. conversions/transposes/invnorm
    prep_k<<<5120, 256, 0, stream>>>(a);

    // 2. G1 (512x1024x2048, KS=4) + G2 (1024x1024x1024, KS=2) — 256 blocks
    GP g1 = {a.A1, a.Bt1, a.P1, S_, E_, D_, 512, 8, 4};
    GP g2 = {a.A2, a.Bt2, a.P2, B_, E_, E_, 512, 8, 8};
    gemm_dual<<<256, 256, 0, stream>>>(g1, g2, 128);

    // 3. BN stats (split-K reduce + partials) — 192 blocks
    bn_stats12<<<192, 256, 0, stream>>>(a);

    // 4. BN finalize + tanh (+fc3) — 96 blocks
    bn_apply12<<<96, 256, 0, stream>>>(a);

    // 5. G3: a_s partials = Wv3 @ Ws^T (1024x512x1024, KS=4) — 128 blocks
    GP g3 = {a.Wv3, a.Ws, a.P3, B_, S_, E_, 256, 4, 8};
    gemm_one<<<128, 256, 0, stream>>>(g3);

    // 6. softmax (reduce KS=4) + A4 = bf16(w * invn) — 512 blocks
    softmax_k<<<512, 256, 0, stream>>>(a);

    // 7. G4: emb_pre = A4 @ cfT^T (1024x2048x512, KS=1) — 128 blocks
    GP g4 = {a.A4, a.cfT, a.emb_pre, B_, D_, S_, S_, 16, 8};
    gemm_one<<<128, 256, 0, stream>>>(g4);

    // 8. emb_concept = l2norm(emb_pre)
    rownorm_k<<<1024, 256, 0, stream>>>(a);
}

// Round 13
// 80.055 us; speedup vs baseline: 1.2657x; 1.2657x over previous
//
#include <hip/hip_runtime.h>
#include <hip/hip_bf16.h>
#include <math.h>

#define B_ 1024
#define S_ 512
#define E_ 1024
#define D_ 2048
#define SMOOTH 10.0f

typedef __attribute__((ext_vector_type(8))) short bf16x8;
typedef __attribute__((ext_vector_type(4))) short s16x4;
typedef __attribute__((ext_vector_type(4))) float f32x4;

__device__ __forceinline__ short f2bf(float f) {
    __hip_bfloat16 h = __float2bfloat16(f);
    short s; __builtin_memcpy(&s, &h, 2); return s;
}

__device__ __forceinline__ void gload16(const short* g, short* l) {
    __builtin_amdgcn_global_load_lds(
        (const __attribute__((address_space(1))) void*)(g),
        (__attribute__((address_space(3))) void*)(l), 16, 0, 0);
}

__inline__ __device__ float waveReduceMax(float v) {
#pragma unroll
    for (int o = 32; o; o >>= 1) v = fmaxf(v, __shfl_xor(v, o));
    return v;
}
__inline__ __device__ float waveReduceSum(float v) {
#pragma unroll
    for (int o = 32; o; o >>= 1) v += __shfl_xor(v, o);
    return v;
}

// ---------------- args ----------------
struct KArgs {
    const float *cf, *emb, *fc1w, *fc2w, *bn1g, *bn1b, *bn2g, *bn2b, *fc3w;
    short *A1, *A2, *Bt1, *Bt2, *cfT, *Ws, *Wv3, *A4;
    float *invn, *Z1, *Z2, *part1, *part2, *P1, *P2, *P3, *P4;
    float *weights_v, *emb_concept;
};

// ---------------- vectorized transpose (32x32 tile via LDS), bf16 out ----------------
__device__ __forceinline__ void transpose_bf(const float* __restrict__ in,
                                             short* __restrict__ out,
                                             int C, int r0, int c0, int ldo,
                                             int tid, float (*t)[33]) {
    {
        int r = tid >> 3, cq = tid & 7;
        f32x4 v = *(const f32x4*)(in + (size_t)(r0 + r) * C + c0 + cq * 4);
#pragma unroll
        for (int i = 0; i < 4; i++) t[r][cq * 4 + i] = v[i];
    }
    __syncthreads();
    {
        int rq = tid & 7, cy = tid >> 3;
        s16x4 o;
#pragma unroll
        for (int i = 0; i < 4; i++) o[i] = f2bf(t[rq * 4 + i][cy]);
        *(s16x4*)(out + (size_t)(c0 + cy) * ldo + r0 + rq * 4) = o;
    }
}

// ---------------- prep: conversions / transposes / invnorm, task-segmented ----------------
__global__ __launch_bounds__(256) void prep_k(KArgs a) {
    __shared__ float t[32][33];
    __shared__ float red[4];
    const int task = blockIdx.x;
    const int tid = threadIdx.x;
    if (task < 512) {
        int row = task;
        const float* x = a.cf + (size_t)row * D_;
        short* aa = a.A1 + (size_t)row * D_;
        float ss = 0.f;
#pragma unroll
        for (int j = 0; j < 2; j++) {
            int i = (j * 256 + tid) * 4;
            f32x4 v = *(const f32x4*)(x + i);
            s16x4 o;
#pragma unroll
            for (int q = 0; q < 4; q++) { o[q] = f2bf(v[q]); ss += v[q] * v[q]; }
            *(s16x4*)(aa + i) = o;
        }
        ss = waveReduceSum(ss);
        if ((tid & 63) == 0) red[tid >> 6] = ss;
        __syncthreads();
        if (tid == 0) {
            float s = red[0] + red[1] + red[2] + red[3];
            a.invn[row] = 1.0f / (sqrtf(s) + 1e-8f);
        }
    } else if (task < 1024) {
        int r0 = (task - 512) * 2;
#pragma unroll
        for (int rr = 0; rr < 2; rr++) {
            int row = r0 + rr;
            int i = tid * 4;
            f32x4 v = *(const f32x4*)(a.emb + (size_t)row * E_ + i);
            s16x4 o;
#pragma unroll
            for (int q = 0; q < 4; q++) o[q] = f2bf(v[q]);
            *(s16x4*)(a.A2 + (size_t)row * E_ + i) = o;
        }
    } else if (task < 3072) {
        int b2 = task - 1024;
        int c0 = (b2 & 31) * 32;
        int r0 = (b2 >> 5) * 32;
        transpose_bf(a.fc1w, a.Bt1, E_, r0, c0, D_, tid, t);
    } else if (task < 4096) {
        int b2 = task - 3072;
        int c0 = (b2 & 31) * 32;
        int r0 = (b2 >> 5) * 32;
        transpose_bf(a.fc2w, a.Bt2, E_, r0, c0, E_, tid, t);
    } else {
        int b2 = task - 4096;
        int c0 = (b2 & 63) * 32;
        int r0 = (b2 >> 6) * 32;
        transpose_bf(a.cf, a.cfT, D_, r0, c0, S_, tid, t);
    }
}

// ---------------- 128x128 MFMA GEMM core, nt form, split-K ----------------
struct GP {
    const short* A;
    const short* Bm;
    float* P;
    int M, N, K, Kc, nx, ny;
};

__device__ __forceinline__ void gemm128_core(const GP g, int bid, short* lds) {
    const int tid = threadIdx.x;
    const int per = g.nx * g.ny;
    const int z = bid / per, rem = bid % per;
    const int by = rem / g.nx, bx = rem % g.nx;
    const int bm = by * 128, bn = bx * 128;
    const int kz = z * g.Kc;
    float* C = g.P + (size_t)z * g.M * g.N;
    const short* gA = g.A + (size_t)bm * g.K + kz;
    const short* gB = g.Bm + (size_t)bn * g.K + kz;

    size_t soff[4];
#pragma unroll
    for (int i = 0; i < 4; i++) {
        int ci = tid + i * 256;
        int row = ci >> 3, c = ci & 7;
        soff[i] = (size_t)row * g.K + ((c ^ (row & 7)) << 3);
    }

    auto stage = [&](int buf, int kt) {
        short* base = lds + buf * 16384;
#pragma unroll
        for (int i = 0; i < 4; i++) {
            gload16(gA + soff[i] + kt, base + tid * 8 + i * 2048);
            gload16(gB + soff[i] + kt, base + 8192 + tid * 8 + i * 2048);
        }
    };

    const int lane = tid & 63, wid = tid >> 6;
    const int wr = wid >> 1, wc = wid & 1;
    const int r16 = lane & 15, kg = lane >> 4;
    const int rs7 = (r16 & 7);

    f32x4 acc[4][4] = {};
    const int nt = g.Kc >> 6;

    stage(0, 0);
    for (int t = 0; t < nt; ++t) {
        __syncthreads();
        if (t + 1 < nt) stage((t + 1) & 1, (t + 1) << 6);
        const short* LA = lds + (t & 1) * 16384;
        const short* LB = LA + 8192;
#pragma unroll
        for (int ks = 0; ks < 2; ++ks) {
            const int sw = ((ks * 4 + kg) ^ rs7) << 3;
            bf16x8 a[4], b[4];
#pragma unroll
            for (int m = 0; m < 4; m++)
                a[m] = *(const bf16x8*)(LA + (wr * 64 + m * 16 + r16) * 64 + sw);
#pragma unroll
            for (int n = 0; n < 4; n++)
                b[n] = *(const bf16x8*)(LB + (wc * 64 + n * 16 + r16) * 64 + sw);
#pragma unroll
            for (int m = 0; m < 4; m++)
#pragma unroll
                for (int n = 0; n < 4; n++)
                    acc[m][n] = __builtin_amdgcn_mfma_f32_16x16x32_bf16(a[m], b[n], acc[m][n], 0, 0, 0);
        }
    }

#pragma unroll
    for (int m = 0; m < 4; m++)
#pragma unroll
        for (int n = 0; n < 4; n++) {
            int col = bn + wc * 64 + n * 16 + r16;
#pragma unroll
            for (int r = 0; r < 4; r++) {
                int row = bm + wr * 64 + m * 16 + kg * 4 + r;
                C[(size_t)row * g.N + col] = acc[m][n][r];
            }
        }
}

__global__ __launch_bounds__(256) void gemm_dual(GP g0, GP g1, int n0) {
    __shared__ short lds[32768];
    int bid = blockIdx.x;
    if (bid < n0) gemm128_core(g0, bid, lds);
    else gemm128_core(g1, bid - n0, lds);
}

__global__ __launch_bounds__(256) void gemm_one(GP g) {
    __shared__ short lds[32768];
    gemm128_core(g, blockIdx.x, lds);
}

// ---------------- split-K reduce + BN partial stats (R8-proven geometry) ----------------
// grid (4, 64): y<32 -> branch1 (16 rows, KS=8); y>=32 -> branch2 (32 rows, KS=4)
__global__ __launch_bounds__(256) void bn_stats12(KArgs a) {
    int c = blockIdx.x * 256 + threadIdx.x;
    if (blockIdx.y < 32) {
        int r0 = blockIdx.y * 16;
        float s = 0.f, ss = 0.f;
        for (int r = r0; r < r0 + 16; r++) {
            float z = 0.f;
#pragma unroll
            for (int k = 0; k < 8; k++) z += a.P1[(size_t)k * S_ * E_ + (size_t)r * E_ + c];
            a.Z1[(size_t)r * E_ + c] = z;
            s += z; ss += z * z;
        }
        a.part1[(size_t)blockIdx.y * 2 * E_ + c] = s;
        a.part1[(size_t)blockIdx.y * 2 * E_ + E_ + c] = ss;
    } else {
        int y2 = blockIdx.y - 32;
        int r0 = y2 * 32;
        float s = 0.f, ss = 0.f;
        for (int r = r0; r < r0 + 32; r++) {
            float z = 0.f;
#pragma unroll
            for (int k = 0; k < 4; k++) z += a.P2[(size_t)k * B_ * E_ + (size_t)r * E_ + c];
            a.Z2[(size_t)r * E_ + c] = z;
            s += z; ss += z * z;
        }
        a.part2[(size_t)y2 * 2 * E_ + c] = s;
        a.part2[(size_t)y2 * 2 * E_ + E_ + c] = ss;
    }
}

// ---------------- BN finalize + tanh (+fc3 scale) -> bf16 (R8-proven geometry) ----------------
__global__ __launch_bounds__(256) void bn_apply12(KArgs a) {
    int c = blockIdx.x * 256 + threadIdx.x;
    bool br1 = blockIdx.y < 32;
    const float* part = br1 ? a.part1 : a.part2;
    float s = 0.f, ss = 0.f;
#pragma unroll
    for (int k = 0; k < 32; k++) {
        s += part[(size_t)k * 2 * E_ + c];
        ss += part[(size_t)k * 2 * E_ + E_ + c];
    }
    float invR = br1 ? (1.0f / 512.0f) : (1.0f / 1024.0f);
    float mu = s * invR;
    float var = ss * invR - mu * mu;
    float rstd = rsqrtf(var + 1e-5f);
    float Aa = (br1 ? a.bn1g[c] : a.bn2g[c]) * rstd;
    float Bb = (br1 ? a.bn1b[c] : a.bn2b[c]) - Aa * mu;
    float sc = br1 ? 1.0f : a.fc3w[c];
    const float* Z = br1 ? a.Z1 : a.Z2;
    short* W = br1 ? a.Ws : a.Wv3;
    int nr = br1 ? 16 : 32;
    int r0 = (br1 ? blockIdx.y : (blockIdx.y - 32)) * nr;
    for (int r = r0; r < r0 + nr; r++) {
        float w = tanhf(fmaf(Z[(size_t)r * E_ + c], Aa, Bb)) * sc;
        W[(size_t)r * E_ + c] = f2bf(w);
    }
}

// ---------------- split-K reduce (KS=8) + row softmax, float4, 2 rows/block ----------------
__global__ __launch_bounds__(256) void softmax_k(KArgs a) {
    __shared__ float redm[4], reds[4];
    const int tid = threadIdx.x;
    const int row = blockIdx.x * 2 + (tid >> 7);
    const int li = (tid & 127) * 4;
    const int wid = tid >> 6;
    const size_t base = (size_t)row * S_ + li;
    f32x4 v = {0, 0, 0, 0};
#pragma unroll
    for (int k = 0; k < 8; k++)
        v += *(const f32x4*)(a.P3 + (size_t)k * B_ * S_ + base);
    v *= SMOOTH;
    float m = fmaxf(fmaxf(v[0], v[1]), fmaxf(v[2], v[3]));
    m = waveReduceMax(m);
    if ((tid & 63) == 0) redm[wid] = m;
    __syncthreads();
    m = (tid < 128) ? fmaxf(redm[0], redm[1]) : fmaxf(redm[2], redm[3]);
    f32x4 e;
#pragma unroll
    for (int q = 0; q < 4; q++) e[q] = __expf(v[q] - m);
    float es = waveReduceSum(e[0] + e[1] + e[2] + e[3]);
    if ((tid & 63) == 0) reds[wid] = es;
    __syncthreads();
    float ssum = (tid < 128) ? (reds[0] + reds[1]) : (reds[2] + reds[3]);
    float inv = 1.0f / ssum;
    f32x4 wv = e * inv;
    *(f32x4*)(a.weights_v + base) = wv;
    f32x4 nv = *(const f32x4*)(a.invn + li);
    s16x4 o;
#pragma unroll
    for (int q = 0; q < 4; q++) o[q] = f2bf(wv[q] * nv[q]);
    *(s16x4*)(a.A4 + base) = o;
}

// ---------------- reduce 2 slices + row l2norm -> output, float4 ----------------
__global__ __launch_bounds__(256) void rownorm2(KArgs a) {
    __shared__ float red[4];
    const int row = blockIdx.x;
    const int tid = threadIdx.x;
    const size_t base = (size_t)row * D_ + tid * 4;
    const size_t sl = (size_t)B_ * D_;
    f32x4 v0 = *(const f32x4*)(a.P4 + base) + *(const f32x4*)(a.P4 + sl + base);
    f32x4 v1 = *(const f32x4*)(a.P4 + base + 1024) + *(const f32x4*)(a.P4 + sl + base + 1024);
    float ss = v0[0]*v0[0] + v0[1]*v0[1] + v0[2]*v0[2] + v0[3]*v0[3]
             + v1[0]*v1[0] + v1[1]*v1[1] + v1[2]*v1[2] + v1[3]*v1[3];
    ss = waveReduceSum(ss);
    if ((tid & 63) == 0) red[tid >> 6] = ss;
    __syncthreads();
    ss = red[0] + red[1] + red[2] + red[3];
    float sc = 1.0f / (sqrtf(ss) + 1e-8f);
    *(f32x4*)(a.emb_concept + base) = v0 * sc;
    *(f32x4*)(a.emb_concept + base + 1024) = v1 * sc;
}

extern "C" void kernel_launch(void* const* d_in, const int* in_sizes, int n_in,
                              void* d_out, int out_size, void* d_ws, size_t ws_size,
                              hipStream_t stream) {
    float* out = (float*)d_out;
    const size_t MB = 1024 * 1024;
    char* w = (char*)d_ws;

    KArgs a;
    a.cf   = (const float*)d_in[1];
    a.emb  = (const float*)d_in[0];
    a.fc1w = (const float*)d_in[3];
    a.fc2w = (const float*)d_in[7];
    a.bn1g = (const float*)d_in[5];
    a.bn1b = (const float*)d_in[6];
    a.bn2g = (const float*)d_in[9];
    a.bn2b = (const float*)d_in[10];
    a.fc3w = (const float*)d_in[11];
    a.Bt1  = (short*)(w + 0 * MB);            // 4MB
    a.Bt2  = (short*)(w + 4 * MB);            // 2MB
    a.A1   = (short*)(w + 6 * MB);            // 2MB
    a.A2   = (short*)(w + 8 * MB);            // 2MB
    a.cfT  = (short*)(w + 10 * MB);           // 2MB
    a.Ws   = (short*)(w + 12 * MB);           // 1MB
    a.Wv3  = (short*)(w + 13 * MB);           // 2MB
    a.A4   = (short*)(w + 15 * MB);           // 1MB
    a.invn = (float*)(w + 16 * MB);           // 2KB
    a.Z1   = (float*)(w + 17 * MB);           // 2MB
    a.Z2   = (float*)(w + 19 * MB);           // 4MB
    a.part1 = (float*)(w + 23 * MB);          // 32*2*E*4 = 256KB
    a.part2 = (float*)(w + 23 * MB + 512 * 1024);
    a.P1   = (float*)(w + 25 * MB);           // KS=8 x 2MB = 16MB
    a.P2   = (float*)(w + 41 * MB);           // KS=4 x 4MB = 16MB
    a.P3   = (float*)(w + 25 * MB);           // KS=8 x 2MB = 16MB (aliases P1, dead after bn_stats)
    a.P4   = (float*)(w + 41 * MB);           // KS=2 x 8MB = 16MB (aliases P2, dead after bn_stats)
    a.emb_concept = out;
    a.weights_v   = out + (size_t)B_ * D_;

    // 1. conversions/transposes/invnorm
    prep_k<<<5120, 256, 0, stream>>>(a);

    // 2. G1 (512x1024x2048, KS=8) + G2 (1024x1024x1024, KS=4) — 512 blocks (R6 geometry)
    GP g1 = {a.A1, a.Bt1, a.P1, S_, E_, D_, 256, 8, 4};
    GP g2 = {a.A2, a.Bt2, a.P2, B_, E_, E_, 256, 8, 8};
    gemm_dual<<<512, 256, 0, stream>>>(g1, g2, 256);

    // 3. BN stats (split-K reduce + partials) — (4,64) = 256 blocks
    bn_stats12<<<dim3(4, 64), 256, 0, stream>>>(a);

    // 4. BN finalize + tanh (+fc3) — (4,64) = 256 blocks
    bn_apply12<<<dim3(4, 64), 256, 0, stream>>>(a);

    // 5. G3: a_s partials = Wv3 @ Ws^T (1024x512x1024, KS=8) — 256 blocks
    GP g3 = {a.Wv3, a.Ws, a.P3, B_, S_, E_, 128, 4, 8};
    gemm_one<<<256, 256, 0, stream>>>(g3);

    // 6. softmax (reduce KS=8) + A4 = bf16(w * invn) — 512 blocks
    softmax_k<<<512, 256, 0, stream>>>(a);

    // 7. G4: emb_pre partials = A4 @ cfT^T (1024x2048x512, KS=2) — 256 blocks
    GP g4 = {a.A4, a.cfT, a.P4, B_, D_, S_, 256, 16, 8};
    gemm_one<<<256, 256, 0, stream>>>(g4);

    // 8. emb_concept = l2norm(P4_0 + P4_1) — 1024 blocks
    rownorm2<<<1024, 256, 0, stream>>>(a);
}

// Round 14
// 73.772 us; speedup vs baseline: 1.3735x; 1.0852x over previous
//
#include <hip/hip_runtime.h>
#include <hip/hip_bf16.h>
#include <math.h>

#define B_ 1024
#define S_ 512
#define E_ 1024
#define D_ 2048
#define SMOOTH 10.0f

typedef __attribute__((ext_vector_type(8))) short bf16x8;
typedef __attribute__((ext_vector_type(4))) short s16x4;
typedef __attribute__((ext_vector_type(4))) float f32x4;

__device__ __forceinline__ short f2bf(float f) {
    __hip_bfloat16 h = __float2bfloat16(f);
    short s; __builtin_memcpy(&s, &h, 2); return s;
}

__device__ __forceinline__ void gload16(const short* g, short* l) {
    __builtin_amdgcn_global_load_lds(
        (const __attribute__((address_space(1))) void*)(g),
        (__attribute__((address_space(3))) void*)(l), 16, 0, 0);
}

__inline__ __device__ float waveReduceMax(float v) {
#pragma unroll
    for (int o = 32; o; o >>= 1) v = fmaxf(v, __shfl_xor(v, o));
    return v;
}
__inline__ __device__ float waveReduceSum(float v) {
#pragma unroll
    for (int o = 32; o; o >>= 1) v += __shfl_xor(v, o);
    return v;
}

// ---------------- args ----------------
struct KArgs {
    const float *cf, *emb, *fc1w, *fc2w, *bn1g, *bn1b, *bn2g, *bn2b, *fc3w;
    short *A1, *A2, *Bt1, *Bt2, *cfT, *Ws, *Wv3, *A4;
    float *invn, *Z1, *Z2, *part1, *part2, *P3, *emb_pre;
    float *weights_v, *emb_concept;
};

// ---------------- vectorized transpose (32x32 tile via LDS), bf16 out ----------------
__device__ __forceinline__ void transpose_bf(const float* __restrict__ in,
                                             short* __restrict__ out,
                                             int C, int r0, int c0, int ldo,
                                             int tid, float (*t)[33]) {
    {
        int r = tid >> 3, cq = tid & 7;
        f32x4 v = *(const f32x4*)(in + (size_t)(r0 + r) * C + c0 + cq * 4);
#pragma unroll
        for (int i = 0; i < 4; i++) t[r][cq * 4 + i] = v[i];
    }
    __syncthreads();
    {
        int rq = tid & 7, cy = tid >> 3;
        s16x4 o;
#pragma unroll
        for (int i = 0; i < 4; i++) o[i] = f2bf(t[rq * 4 + i][cy]);
        *(s16x4*)(out + (size_t)(c0 + cy) * ldo + r0 + rq * 4) = o;
    }
}

// ---------------- prep: conversions / transposes / invnorm ----------------
__global__ __launch_bounds__(256) void prep_k(KArgs a) {
    __shared__ float t[32][33];
    __shared__ float red[4];
    const int task = blockIdx.x;
    const int tid = threadIdx.x;
    if (task < 512) {
        int row = task;
        const float* x = a.cf + (size_t)row * D_;
        short* aa = a.A1 + (size_t)row * D_;
        float ss = 0.f;
#pragma unroll
        for (int j = 0; j < 2; j++) {
            int i = (j * 256 + tid) * 4;
            f32x4 v = *(const f32x4*)(x + i);
            s16x4 o;
#pragma unroll
            for (int q = 0; q < 4; q++) { o[q] = f2bf(v[q]); ss += v[q] * v[q]; }
            *(s16x4*)(aa + i) = o;
        }
        ss = waveReduceSum(ss);
        if ((tid & 63) == 0) red[tid >> 6] = ss;
        __syncthreads();
        if (tid == 0) {
            float s = red[0] + red[1] + red[2] + red[3];
            a.invn[row] = 1.0f / (sqrtf(s) + 1e-8f);
        }
    } else if (task < 1024) {
        int r0 = (task - 512) * 2;
#pragma unroll
        for (int rr = 0; rr < 2; rr++) {
            int row = r0 + rr;
            int i = tid * 4;
            f32x4 v = *(const f32x4*)(a.emb + (size_t)row * E_ + i);
            s16x4 o;
#pragma unroll
            for (int q = 0; q < 4; q++) o[q] = f2bf(v[q]);
            *(s16x4*)(a.A2 + (size_t)row * E_ + i) = o;
        }
    } else if (task < 3072) {
        int b2 = task - 1024;
        int c0 = (b2 & 31) * 32;
        int r0 = (b2 >> 5) * 32;
        transpose_bf(a.fc1w, a.Bt1, E_, r0, c0, D_, tid, t);
    } else if (task < 4096) {
        int b2 = task - 3072;
        int c0 = (b2 & 31) * 32;
        int r0 = (b2 >> 5) * 32;
        transpose_bf(a.fc2w, a.Bt2, E_, r0, c0, E_, tid, t);
    } else {
        int b2 = task - 4096;
        int c0 = (b2 & 63) * 32;
        int r0 = (b2 >> 6) * 32;
        transpose_bf(a.cf, a.cfT, D_, r0, c0, S_, tid, t);
    }
}

// ================= 64x128-tile GEMM core, nt form, KS=1, fused column stats =================
// tile: 64 rows x 128 cols, BK=64; 4 waves (2 wr x 2 wc), wave = 32 x 64.
// Writes Z (full-K result) + part[by][2N]: colsum at [col], colsumsq at [N+col].
struct GP64 {
    const short* A;    // M x K
    const short* Bm;   // N x K
    float* Z;          // M x N
    float* part;       // [M/64][2N]
    int M, N, K, nx;   // nx = N/128
};

__device__ __forceinline__ void gemm64_core(const GP64 g, int bid, short* lds) {
    const int tid = threadIdx.x;
    const int by = bid / g.nx, bx = bid % g.nx;
    const int bm = by * 64, bn = bx * 128;
    const short* gA = g.A + (size_t)bm * g.K;
    const short* gB = g.Bm + (size_t)bn * g.K;

    size_t aoff[2], boff[4];
#pragma unroll
    for (int i = 0; i < 2; i++) {
        int ci = tid + i * 256;
        int row = ci >> 3, c = ci & 7;
        aoff[i] = (size_t)row * g.K + ((c ^ (row & 7)) << 3);
    }
#pragma unroll
    for (int i = 0; i < 4; i++) {
        int ci = tid + i * 256;
        int row = ci >> 3, c = ci & 7;
        boff[i] = (size_t)row * g.K + ((c ^ (row & 7)) << 3);
    }

    auto stage = [&](int buf, int kt) {
        short* base = lds + buf * 12288;          // 24KB per buffer
#pragma unroll
        for (int i = 0; i < 2; i++)
            gload16(gA + aoff[i] + kt, base + tid * 8 + i * 2048);
#pragma unroll
        for (int i = 0; i < 4; i++)
            gload16(gB + boff[i] + kt, base + 4096 + tid * 8 + i * 2048);
    };

    const int lane = tid & 63, wid = tid >> 6;
    const int wr = wid >> 1, wc = wid & 1;
    const int r16 = lane & 15, kg = lane >> 4;
    const int rs7 = r16 & 7;

    f32x4 acc[2][4] = {};
    const int nt = g.K >> 6;

    stage(0, 0);
    for (int t = 0; t < nt; ++t) {
        __syncthreads();
        if (t + 1 < nt) stage((t + 1) & 1, (t + 1) << 6);
        const short* LA = lds + (t & 1) * 12288;
        const short* LB = LA + 4096;
#pragma unroll
        for (int ks = 0; ks < 2; ++ks) {
            const int sw = ((ks * 4 + kg) ^ rs7) << 3;
            bf16x8 av[2], bv[4];
#pragma unroll
            for (int m = 0; m < 2; m++)
                av[m] = *(const bf16x8*)(LA + (wr * 32 + m * 16 + r16) * 64 + sw);
#pragma unroll
            for (int n = 0; n < 4; n++)
                bv[n] = *(const bf16x8*)(LB + (wc * 64 + n * 16 + r16) * 64 + sw);
#pragma unroll
            for (int m = 0; m < 2; m++)
#pragma unroll
                for (int n = 0; n < 4; n++)
                    acc[m][n] = __builtin_amdgcn_mfma_f32_16x16x32_bf16(av[m], bv[n], acc[m][n], 0, 0, 0);
        }
    }

    // write Z
#pragma unroll
    for (int m = 0; m < 2; m++)
#pragma unroll
        for (int n = 0; n < 4; n++) {
            int col = bn + wc * 64 + n * 16 + r16;
#pragma unroll
            for (int r = 0; r < 4; r++) {
                int row = bm + wr * 32 + m * 16 + kg * 4 + r;
                g.Z[(size_t)row * g.N + col] = acc[m][n][r];
            }
        }

    // fused column stats: per-lane partial over its 8 rows, per n
    float cs[4], cq[4];
#pragma unroll
    for (int n = 0; n < 4; n++) {
        float s = 0.f, q = 0.f;
#pragma unroll
        for (int m = 0; m < 2; m++)
#pragma unroll
            for (int r = 0; r < 4; r++) {
                float v = acc[m][n][r];
                s += v; q += v * v;
            }
        cs[n] = s; cq[n] = q;
    }
    // reduce over kg (lanes xor 16, 32): full wave-rows (32) per column
#pragma unroll
    for (int n = 0; n < 4; n++) {
        cs[n] += __shfl_xor(cs[n], 16); cq[n] += __shfl_xor(cq[n], 16);
        cs[n] += __shfl_xor(cs[n], 32); cq[n] += __shfl_xor(cq[n], 32);
    }
    __syncthreads();                      // done reading LDS tiles
    float* sred = (float*)lds;            // 2(wr) x 2(wc) x 4(n) x 16(r16) x 2
    if (kg == 0) {
#pragma unroll
        for (int n = 0; n < 4; n++) {
            int idx = (((wr * 2 + wc) * 4 + n) * 16 + r16) * 2;
            sred[idx] = cs[n];
            sred[idx + 1] = cq[n];
        }
    }
    __syncthreads();
    if (tid < 128) {                      // one thread per tile column
        int wcc = tid >> 6, n = (tid >> 4) & 3, r = tid & 15;
        int i0 = (((0 * 2 + wcc) * 4 + n) * 16 + r) * 2;
        int i1 = (((1 * 2 + wcc) * 4 + n) * 16 + r) * 2;
        int col = bn + wcc * 64 + n * 16 + r;
        g.part[(size_t)by * 2 * g.N + col] = sred[i0] + sred[i1];
        g.part[(size_t)by * 2 * g.N + g.N + col] = sred[i0 + 1] + sred[i1 + 1];
    }
}

__global__ __launch_bounds__(256) void gemm_dual64(GP64 g0, GP64 g1, int n0) {
    __shared__ short lds[24576];          // 48KB
    int bid = blockIdx.x;
    if (bid < n0) gemm64_core(g0, bid, lds);
    else gemm64_core(g1, bid - n0, lds);
}

// ---------------- 128x128 MFMA GEMM core (R8-proven) ----------------
struct GP {
    const short* A;
    const short* Bm;
    float* P;
    int M, N, K, Kc, nx, ny;
};

__device__ __forceinline__ void gemm128_core(const GP g, int bid, short* lds) {
    const int tid = threadIdx.x;
    const int per = g.nx * g.ny;
    const int z = bid / per, rem = bid % per;
    const int by = rem / g.nx, bx = rem % g.nx;
    const int bm = by * 128, bn = bx * 128;
    const int kz = z * g.Kc;
    float* C = g.P + (size_t)z * g.M * g.N;
    const short* gA = g.A + (size_t)bm * g.K + kz;
    const short* gB = g.Bm + (size_t)bn * g.K + kz;

    size_t soff[4];
#pragma unroll
    for (int i = 0; i < 4; i++) {
        int ci = tid + i * 256;
        int row = ci >> 3, c = ci & 7;
        soff[i] = (size_t)row * g.K + ((c ^ (row & 7)) << 3);
    }

    auto stage = [&](int buf, int kt) {
        short* base = lds + buf * 16384;
#pragma unroll
        for (int i = 0; i < 4; i++) {
            gload16(gA + soff[i] + kt, base + tid * 8 + i * 2048);
            gload16(gB + soff[i] + kt, base + 8192 + tid * 8 + i * 2048);
        }
    };

    const int lane = tid & 63, wid = tid >> 6;
    const int wr = wid >> 1, wc = wid & 1;
    const int r16 = lane & 15, kg = lane >> 4;
    const int rs7 = (r16 & 7);

    f32x4 acc[4][4] = {};
    const int nt = g.Kc >> 6;

    stage(0, 0);
    for (int t = 0; t < nt; ++t) {
        __syncthreads();
        if (t + 1 < nt) stage((t + 1) & 1, (t + 1) << 6);
        const short* LA = lds + (t & 1) * 16384;
        const short* LB = LA + 8192;
#pragma unroll
        for (int ks = 0; ks < 2; ++ks) {
            const int sw = ((ks * 4 + kg) ^ rs7) << 3;
            bf16x8 a[4], b[4];
#pragma unroll
            for (int m = 0; m < 4; m++)
                a[m] = *(const bf16x8*)(LA + (wr * 64 + m * 16 + r16) * 64 + sw);
#pragma unroll
            for (int n = 0; n < 4; n++)
                b[n] = *(const bf16x8*)(LB + (wc * 64 + n * 16 + r16) * 64 + sw);
#pragma unroll
            for (int m = 0; m < 4; m++)
#pragma unroll
                for (int n = 0; n < 4; n++)
                    acc[m][n] = __builtin_amdgcn_mfma_f32_16x16x32_bf16(a[m], b[n], acc[m][n], 0, 0, 0);
        }
    }

#pragma unroll
    for (int m = 0; m < 4; m++)
#pragma unroll
        for (int n = 0; n < 4; n++) {
            int col = bn + wc * 64 + n * 16 + r16;
#pragma unroll
            for (int r = 0; r < 4; r++) {
                int row = bm + wr * 64 + m * 16 + kg * 4 + r;
                C[(size_t)row * g.N + col] = acc[m][n][r];
            }
        }
}

__global__ __launch_bounds__(256) void gemm_one(GP g) {
    __shared__ short lds[32768];
    gemm128_core(g, blockIdx.x, lds);
}

// ---------------- BN finalize + tanh (+fc3 scale) -> bf16 ----------------
// grid (4,64): y<32 -> branch1 (NS=8, 16 rows); y>=32 -> branch2 (NS=16, 32 rows)
__global__ __launch_bounds__(256) void bn_apply12(KArgs a) {
    int c = blockIdx.x * 256 + threadIdx.x;
    bool br1 = blockIdx.y < 32;
    const float* part = br1 ? a.part1 : a.part2;
    int NS = br1 ? 8 : 16;
    float s = 0.f, ss = 0.f;
    for (int k = 0; k < NS; k++) {
        s += part[(size_t)k * 2 * E_ + c];
        ss += part[(size_t)k * 2 * E_ + E_ + c];
    }
    float invR = br1 ? (1.0f / 512.0f) : (1.0f / 1024.0f);
    float mu = s * invR;
    float var = ss * invR - mu * mu;
    float rstd = rsqrtf(var + 1e-5f);
    float Aa = (br1 ? a.bn1g[c] : a.bn2g[c]) * rstd;
    float Bb = (br1 ? a.bn1b[c] : a.bn2b[c]) - Aa * mu;
    float sc = br1 ? 1.0f : a.fc3w[c];
    const float* Z = br1 ? a.Z1 : a.Z2;
    short* W = br1 ? a.Ws : a.Wv3;
    int nr = br1 ? 16 : 32;
    int r0 = (br1 ? blockIdx.y : (blockIdx.y - 32)) * nr;
    for (int r = r0; r < r0 + nr; r++) {
        float w = tanhf(fmaf(Z[(size_t)r * E_ + c], Aa, Bb)) * sc;
        W[(size_t)r * E_ + c] = f2bf(w);
    }
}

// ---------------- split-K reduce (KS=4) + row softmax ----------------
__global__ __launch_bounds__(256) void softmax_k(KArgs a) {
    __shared__ float red[4];
    int row = blockIdx.x;
    int tid = threadIdx.x;
    float v0 = 0.f, v1 = 0.f;
#pragma unroll
    for (int k = 0; k < 4; k++) {
        v0 += a.P3[(size_t)k * B_ * S_ + (size_t)row * S_ + tid];
        v1 += a.P3[(size_t)k * B_ * S_ + (size_t)row * S_ + tid + 256];
    }
    v0 *= SMOOTH;
    v1 *= SMOOTH;
    float m = waveReduceMax(fmaxf(v0, v1));
    if ((tid & 63) == 0) red[tid >> 6] = m;
    __syncthreads();
    m = fmaxf(fmaxf(red[0], red[1]), fmaxf(red[2], red[3]));
    float e0 = __expf(v0 - m), e1 = __expf(v1 - m);
    float s = waveReduceSum(e0 + e1);
    __syncthreads();
    if ((tid & 63) == 0) red[tid >> 6] = s;
    __syncthreads();
    s = red[0] + red[1] + red[2] + red[3];
    float inv = 1.0f / s;
    float w0 = e0 * inv, w1 = e1 * inv;
    a.weights_v[(size_t)row * S_ + tid] = w0;
    a.weights_v[(size_t)row * S_ + tid + 256] = w1;
    a.A4[(size_t)row * S_ + tid] = f2bf(w0 * a.invn[tid]);
    a.A4[(size_t)row * S_ + tid + 256] = f2bf(w1 * a.invn[tid + 256]);
}

// ---------------- row l2norm -> output ----------------
__global__ __launch_bounds__(256) void rownorm_k(KArgs a) {
    __shared__ float red[4];
    int row = blockIdx.x;
    int tid = threadIdx.x;
    float v[8];
    float ss = 0.f;
#pragma unroll
    for (int j = 0; j < 8; j++) {
        v[j] = a.emb_pre[(size_t)row * D_ + j * 256 + tid];
        ss += v[j] * v[j];
    }
    ss = waveReduceSum(ss);
    if ((tid & 63) == 0) red[tid >> 6] = ss;
    __syncthreads();
    ss = red[0] + red[1] + red[2] + red[3];
    float sc = 1.0f / (sqrtf(ss) + 1e-8f);
#pragma unroll
    for (int j = 0; j < 8; j++)
        a.emb_concept[(size_t)row * D_ + j * 256 + tid] = v[j] * sc;
}

extern "C" void kernel_launch(void* const* d_in, const int* in_sizes, int n_in,
                              void* d_out, int out_size, void* d_ws, size_t ws_size,
                              hipStream_t stream) {
    float* out = (float*)d_out;
    const size_t MB = 1024 * 1024;
    char* w = (char*)d_ws;

    KArgs a;
    a.cf   = (const float*)d_in[1];
    a.emb  = (const float*)d_in[0];
    a.fc1w = (const float*)d_in[3];
    a.fc2w = (const float*)d_in[7];
    a.bn1g = (const float*)d_in[5];
    a.bn1b = (const float*)d_in[6];
    a.bn2g = (const float*)d_in[9];
    a.bn2b = (const float*)d_in[10];
    a.fc3w = (const float*)d_in[11];
    a.Bt1  = (short*)(w + 0 * MB);            // 4MB
    a.Bt2  = (short*)(w + 4 * MB);            // 2MB
    a.A1   = (short*)(w + 6 * MB);            // 2MB
    a.A2   = (short*)(w + 8 * MB);            // 2MB
    a.cfT  = (short*)(w + 10 * MB);           // 2MB
    a.Ws   = (short*)(w + 12 * MB);           // 1MB
    a.Wv3  = (short*)(w + 13 * MB);           // 2MB
    a.A4   = (short*)(w + 15 * MB);           // 1MB
    a.invn = (float*)(w + 16 * MB);           // 2KB
    a.Z1   = (float*)(w + 17 * MB);           // 2MB
    a.Z2   = (float*)(w + 19 * MB);           // 4MB
    a.part1 = (float*)(w + 23 * MB);          // 8 x 2E x 4B = 64KB
    a.part2 = (float*)(w + 23 * MB + 256 * 1024);  // 16 x 2E x 4B = 128KB
    a.P3   = (float*)(w + 24 * MB);           // KS=4 x 2MB = 8MB
    a.emb_pre = (float*)(w + 32 * MB);        // 8MB
    a.emb_concept = out;
    a.weights_v   = out + (size_t)B_ * D_;

    // 1. conversions/transposes/invnorm
    prep_k<<<5120, 256, 0, stream>>>(a);

    // 2. dual G1 (512x1024x2048) + G2 (1024x1024x1024), 64x128 tiles, KS=1,
    //    fused col-stats -> Z1/Z2 + part1/part2. 64 + 128 = 192 blocks.
    GP64 g1 = {a.A1, a.Bt1, a.Z1, a.part1, S_, E_, D_, 8};
    GP64 g2 = {a.A2, a.Bt2, a.Z2, a.part2, B_, E_, E_, 8};
    gemm_dual64<<<192, 256, 0, stream>>>(g1, g2, 64);

    // 3. BN finalize + tanh (+fc3) — (4,64) = 256 blocks
    bn_apply12<<<dim3(4, 64), 256, 0, stream>>>(a);

    // 4. G3: a_s partials = Wv3 @ Ws^T (1024x512x1024, KS=4) — 128 blocks (R8 exact)
    GP g3 = {a.Wv3, a.Ws, a.P3, B_, S_, E_, 256, 4, 8};
    gemm_one<<<128, 256, 0, stream>>>(g3);

    // 5. softmax (reduce KS=4) + A4 = bf16(w * invn) — 1024 blocks (R8 exact)
    softmax_k<<<B_, 256, 0, stream>>>(a);

    // 6. G4: emb_pre = A4 @ cfT^T (1024x2048x512, KS=1) — 128 blocks (R8 exact)
    GP g4 = {a.A4, a.cfT, a.emb_pre, B_, D_, S_, 512, 16, 8};
    gemm_one<<<128, 256, 0, stream>>>(g4);

    // 7. emb_concept = l2norm(emb_pre) — 1024 blocks (R8 exact)
    rownorm_k<<<B_, 256, 0, stream>>>(a);
}